// Round 1
// baseline (15364.430 us; speedup 1.0000x reference)
//
#include <hip/hip_runtime.h>
#include <hip/hip_fp16.h>
#include <stdint.h>

// Reservoir recurrence, persistent-wave dataflow design.
//   s_{t+1} = tanh(X[t]@W_in_row + 0.9 * W_res @ s_t) / sqrt(2048)
// 512 one-wave blocks; each wave owns 4 rows of W_res in registers.
// State exchanged through 8B LL-units: (2 x f16 data | u32 step tag),
// relaxed agent-scope atomics, double-buffered by step parity.

#define RES     2048
#define UNITS   16            // 8B units polled per lane per step (= RES/128)
#define ROWSPW  4             // state rows per wave
#define NBLK    (RES / ROWSPW) // 512 blocks of 64 threads

__device__ __forceinline__ float fast_tanh(float x) {
  // tanh(x) = 1 - 2/(e^{2x}+1); __expf overflows to +inf -> returns exactly 1,
  // underflows to 0 -> returns exactly -1. Good to ~1e-6 in between.
  float e = __expf(2.0f * x);
  return 1.0f - 2.0f / (e + 1.0f);
}

__global__ void reservoir_init(const float* __restrict__ s0,
                               float* __restrict__ out,
                               uint64_t* __restrict__ buf0,
                               uint64_t* __restrict__ buf1,
                               int res) {
  int i = blockIdx.x * blockDim.x + threadIdx.x;
  if (i < res) out[i] = s0[i];            // output row 0 = initial_state (f32)
  if (i < res / 2) {
    uint32_t a = (uint32_t)__half_as_ushort(__float2half_rn(s0[2 * i]));
    uint32_t b = (uint32_t)__half_as_ushort(__float2half_rn(s0[2 * i + 1]));
    buf0[i] = (uint64_t)(a | (b << 16));  // data in low word, tag 0 in high word
    buf1[i] = 0xFFFFFFFF00000000ull;      // poison tag (never matches 0..4096)
  }
}

__global__ void __launch_bounds__(64, 1)
reservoir_main(const float* __restrict__ in,     // (seq, isz) f32
               const float* __restrict__ W_in,   // (RES, isz) f32
               const float* __restrict__ W_res,  // (RES, RES) f32
               float* __restrict__ out,          // (seq+1, RES) f32
               uint64_t* __restrict__ buf0,
               uint64_t* __restrict__ buf1,
               int seq, int isz) {
  const int lane = threadIdx.x & 63;
  const int wid  = blockIdx.x;       // 0..NBLK-1, one wave per block
  const int r0   = wid * ROWSPW;

  // ---- one-time: gather this wave's W_res rows into registers, pre-scaled by
  // RES_SCALE. Lane l holds columns {2*(l+64j), 2*(l+64j)+1 : j<UNITS} so that
  // the step-time coalesced unit gather (unit index l+64j) lines up exactly.
  float w[ROWSPW][2 * UNITS];
#pragma unroll
  for (int r = 0; r < ROWSPW; ++r) {
    const float* wr = W_res + (size_t)(r0 + r) * RES;
#pragma unroll
    for (int j = 0; j < UNITS; ++j) {
      float2 p = *(const float2*)(wr + 2 * (lane + 64 * j));
      w[r][2 * j]     = 0.9f * p.x;
      w[r][2 * j + 1] = 0.9f * p.y;
    }
  }
  // W_in slice: lane l holds input columns 2l, 2l+1 for its 4 rows.
  float win[ROWSPW][2];
#pragma unroll
  for (int r = 0; r < ROWSPW; ++r) {
    float2 p = *(const float2*)(W_in + (size_t)(r0 + r) * isz + 2 * lane);
    win[r][0] = p.x;
    win[r][1] = p.y;
  }

  const float inv_sqrt_n = 0.022097086912079612f;  // 1/sqrt(2048)

  // prefetch input row 0 (lane l -> cols 2l,2l+1)
  float2 xin = *(const float2*)(in + 2 * lane);

  for (int t = 0; t < seq; ++t) {
    uint64_t* src = (t & 1) ? buf1 : buf0;  // holds s_t (tag == t)
    uint64_t* dst = (t & 1) ? buf0 : buf1;  // will hold s_{t+1} (tag == t+1)
    const uint32_t want = (uint32_t)t;

    // accumulators start with the input projection (INPUT_SCALE = 1.0)
    float acc0 = fmaf(xin.y, win[0][1], xin.x * win[0][0]);
    float acc1 = fmaf(xin.y, win[1][1], xin.x * win[1][0]);
    float acc2 = fmaf(xin.y, win[2][1], xin.x * win[2][0]);
    float acc3 = fmaf(xin.y, win[3][1], xin.x * win[3][0]);

    // ---- poll: 16 coalesced 8B LL-unit loads; tag==t validates the payload
    uint32_t dw[UNITS];
    for (;;) {
      uint64_t v[UNITS];
#pragma unroll
      for (int j = 0; j < UNITS; ++j)
        v[j] = __hip_atomic_load(src + lane + 64 * j, __ATOMIC_RELAXED,
                                 __HIP_MEMORY_SCOPE_AGENT);
      bool ok = true;
#pragma unroll
      for (int j = 0; j < UNITS; ++j)
        ok &= ((uint32_t)(v[j] >> 32) == want);
      if (__all(ok)) {
#pragma unroll
        for (int j = 0; j < UNITS; ++j) dw[j] = (uint32_t)v[j];
        break;
      }
    }

    // ---- matvec partials: W (f32 regs) x state (f16 -> f32)
#pragma unroll
    for (int j = 0; j < UNITS; ++j) {
      float s0 = __half2float(__ushort_as_half((unsigned short)(dw[j] & 0xffffu)));
      float s1 = __half2float(__ushort_as_half((unsigned short)(dw[j] >> 16)));
      acc0 = fmaf(w[0][2 * j], s0, acc0); acc0 = fmaf(w[0][2 * j + 1], s1, acc0);
      acc1 = fmaf(w[1][2 * j], s0, acc1); acc1 = fmaf(w[1][2 * j + 1], s1, acc1);
      acc2 = fmaf(w[2][2 * j], s0, acc2); acc2 = fmaf(w[2][2 * j + 1], s1, acc2);
      acc3 = fmaf(w[3][2 * j], s0, acc3); acc3 = fmaf(w[3][2 * j + 1], s1, acc3);
    }

    // ---- 64-lane butterfly reduction for each owned row
#pragma unroll
    for (int d = 1; d < 64; d <<= 1) {
      acc0 += __shfl_xor(acc0, d);
      acc1 += __shfl_xor(acc1, d);
      acc2 += __shfl_xor(acc2, d);
      acc3 += __shfl_xor(acc3, d);
    }

    // ---- finish: lanes 0..3 hold rows r0..r0+3
    float accsel = (lane == 0) ? acc0 : (lane == 1) ? acc1
                 : (lane == 2) ? acc2 : acc3;
    float o = fast_tanh(accsel) * inv_sqrt_n;

    // pack pairs (lane0: rows 0,1 -> unit 2*wid; lane2: rows 2,3 -> unit 2*wid+1)
    unsigned short ob  = __half_as_ushort(__float2half_rn(o));
    unsigned short obn = (unsigned short)__shfl((int)ob, (lane + 1) & 63);
    if (lane == 0 || lane == 2) {
      uint32_t word = (uint32_t)ob | ((uint32_t)obn << 16);
      uint64_t val  = ((uint64_t)(uint32_t)(t + 1) << 32) | (uint64_t)word;
      __hip_atomic_store(dst + (2 * wid + (lane >> 1)), val, __ATOMIC_RELAXED,
                         __HIP_MEMORY_SCOPE_AGENT);
    }
    // output row t+1 (fire-and-forget)
    if (lane < ROWSPW)
      out[(size_t)(t + 1) * RES + r0 + lane] = o;

    // prefetch next input row (off the critical path)
    int tn = (t + 1 < seq) ? (t + 1) : t;
    xin = *(const float2*)(in + (size_t)tn * isz + 2 * lane);
  }
}

extern "C" void kernel_launch(void* const* d_in, const int* in_sizes, int n_in,
                              void* d_out, int out_size, void* d_ws, size_t ws_size,
                              hipStream_t stream) {
  const float* input = (const float*)d_in[0];   // (seq, isz)
  const float* s0    = (const float*)d_in[1];   // (res,)
  const float* W_in  = (const float*)d_in[2];   // (res, isz)
  const float* W_res = (const float*)d_in[3];   // (res, res)
  float* out = (float*)d_out;

  const int res = in_sizes[1];             // 2048
  const int isz = in_sizes[2] / res;       // 128
  const int seq = in_sizes[0] / isz;       // 4096

  uint64_t* buf0 = (uint64_t*)d_ws;        // res/2 units
  uint64_t* buf1 = buf0 + res / 2;         // res/2 units  (total 16 KB)

  reservoir_init<<<(res + 255) / 256, 256, 0, stream>>>(s0, out, buf0, buf1, res);
  reservoir_main<<<res / ROWSPW, 64, 0, stream>>>(input, W_in, W_res, out,
                                                  buf0, buf1, seq, isz);
}